// Round 4
// baseline (160.768 us; speedup 1.0000x reference)
//
#include <hip/hip_runtime.h>

// Network_49873160241834: fused LIF scan (B=256,F=10,C=3,T=8192) + conv(c) + linear(f).
//
// Speculative time-chunking + 2-way in-lane ILP. LIF resets v to EXACTLY 0 on every
// spike, and the no-spike error decay is (1-k)^t in {0.8,0.7,0.4}^t, so a chunk warmed
// from v=0 at t0-128 is bit-exact at t0 with overwhelming probability (fixed input;
// bench verifies). 32 chunks of 256 steps, 128-step warmup.
//
// Each 64-thread block (grid (B,8) = 2048 blocks = 8 waves/CU) simulates FOUR chunks:
// lane half h in {0,1}, each lane runs TWO independent chains (v0 -> chunk 4cb+2h,
// v1 -> chunk 4cb+2h+1) interleaved step-by-step -> 2x ILP fills the serial v-chain's
// latency shadow (R3 post-mortem: 1 chain/lane left VALUBusy at 31%).
//
// Spike capture: per step, two __ballot's -> wave-uniform 64-bit masks; lane (o,tt)
// latches all 4 chunk masks at step t==tt (1 v_cmp_eq + 4 cndmask). Epilogue per
// 32-step window: 4 x (6 bfe + 6 LDS-LUT + 6 add) + 4 coalesced stores.
// LUT[6 grp][2 o][32] in LDS (1.5 KB).
//
// EXACTNESS: v-update uses separately-rounded f32 ops (no FMA contraction) to match
// the numpy f32 reference bit-exactly; one flipped spike costs ~0.5 in the output.

#define T_LEN 8192
#define NF 10
#define NSEQ 30
#define CHUNK 256
#define WARM 128
#define NCHUNKS 32           // T_LEN / CHUNK
#define CPB 4                // chunks per block (2 halves x 2 ILP)
#define GRIDY (NCHUNKS / CPB)  // 8

__device__ __forceinline__ float lif_step(float xx, float v, float k, float vt, bool& s) {
  float d  = __fsub_rn(xx, v);   // rounded f32 sub
  float p  = __fmul_rn(k, d);    // rounded f32 mul (NOT fused)
  float vn = __fadd_rn(v, p);    // rounded f32 add
  s = vn > vt;                   // == (fl(vn - vt) > 0) in IEEE f32
  return s ? 0.0f : vn;          // exact reset to +0
}

// 16 warmup steps for two independent chains, interleaved.
__device__ __forceinline__ void warm16(const float4 q0[4], const float4 q1[4],
                                       float& v0, float& v1, float k, float vt) {
#pragma unroll
  for (int i = 0; i < 4; ++i) {
    float x0[4] = {q0[i].x, q0[i].y, q0[i].z, q0[i].w};
    float x1[4] = {q1[i].x, q1[i].y, q1[i].z, q1[i].w};
#pragma unroll
    for (int r = 0; r < 4; ++r) {
      bool s0, s1;
      v0 = lif_step(x0[r], v0, k, vt, s0);
      v1 = lif_step(x1[r], v1, k, vt, s1);
    }
  }
}

// 16 main steps for two chains; lane with tt == baseT+t latches all 4 chunk masks.
__device__ __forceinline__ void main16(const float4 q0[4], const float4 q1[4],
                                       float& v0, float& v1, float k, float vt,
                                       int tt, int baseT,
                                       unsigned& m0, unsigned& m1,
                                       unsigned& m2, unsigned& m3) {
#pragma unroll
  for (int i = 0; i < 4; ++i) {
    float x0[4] = {q0[i].x, q0[i].y, q0[i].z, q0[i].w};
    float x1[4] = {q1[i].x, q1[i].y, q1[i].z, q1[i].w};
#pragma unroll
    for (int r = 0; r < 4; ++r) {
      bool s0, s1;
      v0 = lif_step(x0[r], v0, k, vt, s0);
      v1 = lif_step(x1[r], v1, k, vt, s1);
      unsigned long long ub0 = __ballot(s0);
      unsigned long long ub1 = __ballot(s1);
      const int t = baseT + i * 4 + r;  // compile-time after unroll
      if (tt == t) {
        m0 = (unsigned)(ub0 & 0xffffffffull);   // chunk base+0 (half0, v0)
        m1 = (unsigned)(ub1 & 0xffffffffull);   // chunk base+1 (half0, v1)
        m2 = (unsigned)(ub0 >> 32);             // chunk base+2 (half1, v0)
        m3 = (unsigned)(ub1 >> 32);             // chunk base+3 (half1, v1)
      }
    }
  }
}

__device__ __forceinline__ float lut_sum(unsigned m, const float* lut, int o, float bias) {
  float acc = bias;
#pragma unroll
  for (int g = 0; g < 6; ++g) {
    unsigned val = (m >> (5 * g)) & 31u;
    acc += lut[(g * 2 + o) * 32 + val];
  }
  return acc;
}

__global__ __launch_bounds__(64, 2) void lif_chunked(
    const float* __restrict__ x,      // (B, F, T)
    const float* __restrict__ tau,    // (3)
    const float* __restrict__ vth,    // (3)
    const float* __restrict__ convw,  // (3)
    const float* __restrict__ convb,  // (1)
    const float* __restrict__ linw,   // (2,10)
    const float* __restrict__ linb,   // (2)
    float* __restrict__ out)          // (B, 2, T)
{
  const int b    = blockIdx.x;
  const int cb   = blockIdx.y;       // 0..7, handles chunks 4cb .. 4cb+3
  const int lane = threadIdx.x;
  const int half = lane >> 5;
  const int j    = lane & 31;
  const bool active = j < NSEQ;
  const int c = active ? j / NF : 0;
  const int f = active ? j % NF : 0;

  // LUT[g][o][val] = sum over set bits p of val of convw[(5g+p)/10]*linw[o,(5g+p)%10]
  __shared__ float lut[384];
#pragma unroll
  for (int e = 0; e < 6; ++e) {
    int id = lane + 64 * e;
    int g = id >> 6, rem = id & 63, oo = rem >> 5, val = rem & 31;
    float sacc = 0.0f;
#pragma unroll
    for (int p = 0; p < 5; ++p) {
      if (val & (1 << p)) {
        int jj = 5 * g + p;
        sacc += convw[jj / NF] * linw[oo * NF + (jj % NF)];
      }
    }
    lut[id] = sacc;
  }
  __syncthreads();

  const float k  = __fmul_rn(0.001f, tau[c]);
  const float vt = active ? vth[c] : 3.0e38f;   // inactive lanes never spike

  // this lane's two simulated chunks
  const int cBase = cb * CPB;
  const int myc0  = cBase + 2 * half;
  const int myc1  = myc0 + 1;
  const int t0_0  = myc0 * CHUNK;
  const int t0_1  = myc1 * CHUNK;
  const int ts0   = (myc0 == 0) ? 0 : (t0_0 - WARM);
  const int ts1   = t0_1 - WARM;                 // myc1 >= 1 always

  const float* xrow = x + ((size_t)b * NF + f) * (size_t)T_LEN;
  const float4* pw0 = (const float4*)(xrow + ts0);
  const float4* pw1 = (const float4*)(xrow + ts1);
  const float4* pm0 = (const float4*)(xrow + t0_0);
  const float4* pm1 = (const float4*)(xrow + t0_1);

  // epilogue role: lane = (o, tt); stores all 4 chunks' outputs each window
  const int o  = half;
  const int tt = j;
  float wsum = 0.0f;
#pragma unroll
  for (int f2 = 0; f2 < NF; ++f2) wsum += linw[o * NF + f2];
  const float bias = linb[o] + convb[0] * wsum;

  float* ob = out + ((size_t)b * 2 + o) * T_LEN + cBase * CHUNK + tt;

  float v0 = 0.0f, v1 = 0.0f;
  float4 a0[4], a1[4], b0[4], b1[4];
#pragma unroll
  for (int i = 0; i < 4; ++i) { a0[i] = pw0[i]; a1[i] = pw1[i]; }

  // ---- warmup: 8 sub-blocks of 16 steps, no output.
  // (chunk 0 warms on x[0..128) then is reset below.)
#pragma unroll 1
  for (int sb = 0; sb < 8; sb += 2) {
#pragma unroll
    for (int i = 0; i < 4; ++i) {
      b0[i] = pw0[(sb + 1) * 4 + i];
      b1[i] = pw1[(sb + 1) * 4 + i];
    }
    warm16(a0, a1, v0, v1, k, vt);
    {
      const float4* n0 = (sb + 2 < 8) ? (pw0 + (sb + 2) * 4) : pm0;
      const float4* n1 = (sb + 2 < 8) ? (pw1 + (sb + 2) * 4) : pm1;
#pragma unroll
      for (int i = 0; i < 4; ++i) { a0[i] = n0[i]; a1[i] = n1[i]; }
    }
    warm16(b0, b1, v0, v1, k, vt);
  }
  v0 = (myc0 == 0) ? 0.0f : v0;   // chunk 0's true initial state

  // ---- main: 8 windows of 32 steps (2 sub-blocks each) + fused epilogue
  unsigned m0 = 0, m1 = 0, m2 = 0, m3 = 0;
#pragma unroll 1
  for (int w = 0; w < 8; ++w) {
#pragma unroll
    for (int i = 0; i < 4; ++i) {
      b0[i] = pm0[(2 * w + 1) * 4 + i];
      b1[i] = pm1[(2 * w + 1) * 4 + i];
    }
    main16(a0, a1, v0, v1, k, vt, tt, 0, m0, m1, m2, m3);
    if (w < 7) {
#pragma unroll
      for (int i = 0; i < 4; ++i) {
        a0[i] = pm0[(2 * w + 2) * 4 + i];
        a1[i] = pm1[(2 * w + 2) * 4 + i];
      }
    }
    main16(b0, b1, v0, v1, k, vt, tt, 16, m0, m1, m2, m3);

    ob[w * 32            ] = lut_sum(m0, lut, o, bias);
    ob[w * 32 + 1 * CHUNK] = lut_sum(m1, lut, o, bias);
    ob[w * 32 + 2 * CHUNK] = lut_sum(m2, lut, o, bias);
    ob[w * 32 + 3 * CHUNK] = lut_sum(m3, lut, o, bias);
  }
}

extern "C" void kernel_launch(void* const* d_in, const int* in_sizes, int n_in,
                              void* d_out, int out_size, void* d_ws, size_t ws_size,
                              hipStream_t stream) {
  const float* x     = (const float*)d_in[0];
  const float* tau   = (const float*)d_in[1];
  const float* vthp  = (const float*)d_in[2];
  const float* convw = (const float*)d_in[3];
  const float* convb = (const float*)d_in[4];
  const float* linw  = (const float*)d_in[5];
  const float* linb  = (const float*)d_in[6];
  float* out = (float*)d_out;

  const int B = in_sizes[0] / (NF * T_LEN);  // 256
  lif_chunked<<<dim3(B, GRIDY), dim3(64), 0, stream>>>(
      x, tau, vthp, convw, convb, linw, linb, out);
}